// Round 6
// baseline (498.252 us; speedup 1.0000x reference)
//
#include <hip/hip_runtime.h>

// DNNF fused pipeline for MI355X (gfx950). R11 = R7 gemm core (best: 132us)
// + finale fused into the gemm epilogue via per-m-tile completion counters.
// R10 lesson: B-direct-to-reg regressed (strided 64-line gathers through L1);
// staging-BW is NOT the wall. ~100us of the 237 is non-gemm: finale launch +
// form_sum/dotbuf HBM round-trip. Fused finale runs in the 58th (last) block
// of each m-tile column, reading form_sum/dotbuf from the writer XCD's L2
// (grid id%8 = x%8 pins each m-tile to one XCD; correctness is fence-based,
// locality is the heuristic). R9 lesson kept: no launch_bounds below acc=96.

#define BATCH 8192
#define IDIM 512
#define NFORM 256
#define NLIT 10752
#define WT_ROWS 11136  // NLIT + 256 mu + 128 zero pad; /192 = 58 tiles
#define NTILES 58

#define BM 128
#define BN 192
#define BK 32
#define ABYTES 8192    // 128*32*2
#define BUFB 20480     // one LDS buffer: A 8192 + B 12288
#define SLITP 196      // slit row stride (floats)

typedef __bf16 bf16x8 __attribute__((ext_vector_type(8)));
typedef float f32x4 __attribute__((ext_vector_type(4)));
typedef unsigned short u16;
typedef unsigned int u32;

__device__ __forceinline__ u16 f2bf(float f) {
  u32 u = __float_as_uint(f);
  u = (u + 0x7fffu + ((u >> 16) & 1u)) >> 16;  // RNE
  return (u16)u;
}

__device__ __forceinline__ float fast_tanh(float x) {
  float e = __expf(2.0f * x);
  return 1.0f - 2.0f * __builtin_amdgcn_rcpf(e + 1.0f);
}

__device__ __forceinline__ void async_cp16(const void* g, void* l) {
  __builtin_amdgcn_global_load_lds(
      (const u32 __attribute__((address_space(1)))*)g,
      (u32 __attribute__((address_space(3)))*)l, 16, 0, 0);
}

// ---------------- fused prep (one dispatch) ----------------

#define PREPX_BLKS 2048
#define PREPW_BLKS 1344  // 168 l-tiles x 8 k-tiles

__global__ __launch_bounds__(256) void prep_all(
    const float* __restrict__ x, const float* __restrict__ W,
    const float* __restrict__ M, const float* __restrict__ mu,
    u16* __restrict__ xb, u16* __restrict__ wt, float* __restrict__ xsq,
    float* __restrict__ musq, float* __restrict__ form_sum,
    u32* __restrict__ cnt) {
  __shared__ float lds[64 * 65];  // 16.6 KB; also reused as red[256]
  const int blk = blockIdx.x, tid = threadIdx.x;

  if (blk < PREPX_BLKS) {
    if (blk == 0 && tid < 64) cnt[tid] = 0;  // m-tile completion counters
    ((uint4*)form_sum)[blk * 256 + tid] = make_uint4(0, 0, 0, 0);
    int wave = tid >> 6, lane = tid & 63;
    int row = blk * 4 + wave;
    const float4* px = (const float4*)(x + (size_t)row * IDIM);
    float4 a = px[lane * 2], b = px[lane * 2 + 1];
    uint4 pk;
    pk.x = (u32)f2bf(a.x) | ((u32)f2bf(a.y) << 16);
    pk.y = (u32)f2bf(a.z) | ((u32)f2bf(a.w) << 16);
    pk.z = (u32)f2bf(b.x) | ((u32)f2bf(b.y) << 16);
    pk.w = (u32)f2bf(b.z) | ((u32)f2bf(b.w) << 16);
    ((uint4*)(xb + (size_t)row * IDIM))[lane] = pk;
    float s = a.x * a.x + a.y * a.y + a.z * a.z + a.w * a.w +
              b.x * b.x + b.y * b.y + b.z * b.z + b.w * b.w;
#pragma unroll
    for (int o = 32; o > 0; o >>= 1) s += __shfl_down(s, o);
    if (lane == 0) xsq[row] = s;
  } else if (blk < PREPX_BLKS + PREPW_BLKS) {
    int b = blk - PREPX_BLKS;
    int l0 = (b % 168) * 64, k0 = (b / 168) * 64;
#pragma unroll
    for (int j = 0; j < 4; ++j) {
      int idx = tid + j * 256;
      int kk = idx >> 4, l4 = idx & 15;
      size_t g = (size_t)(k0 + kk) * NLIT + l0 + l4 * 4;
      float4 w4 = *(const float4*)(W + g);
      float4 m4 = *(const float4*)(M + g);
      lds[kk * 65 + l4 * 4 + 0] = w4.x * m4.x;
      lds[kk * 65 + l4 * 4 + 1] = w4.y * m4.y;
      lds[kk * 65 + l4 * 4 + 2] = w4.z * m4.z;
      lds[kk * 65 + l4 * 4 + 3] = w4.w * m4.w;
    }
    __syncthreads();
    int l = tid >> 2, kq = tid & 3;
    u32 pk[8];
#pragma unroll
    for (int t = 0; t < 8; ++t) {
      u16 lo = f2bf(lds[(kq * 16 + 2 * t) * 65 + l]);
      u16 hi = f2bf(lds[(kq * 16 + 2 * t + 1) * 65 + l]);
      pk[t] = (u32)lo | ((u32)hi << 16);
    }
    u32* dst = (u32*)(wt + (size_t)(l0 + l) * IDIM + k0 + kq * 16);
    ((uint4*)dst)[0] = make_uint4(pk[0], pk[1], pk[2], pk[3]);
    ((uint4*)dst)[1] = make_uint4(pk[4], pk[5], pk[6], pk[7]);
  } else {
    int b = blk - PREPX_BLKS - PREPW_BLKS;
    if (b < 256) {
      float s = 0.f;
#pragma unroll
      for (int j = tid; j < IDIM; j += 256) {
        float v = mu[(size_t)b * IDIM + j];
        wt[(size_t)(NLIT + b) * IDIM + j] = f2bf(v);
        s += v * v;
      }
      float* red = lds;
      red[tid] = s;
      __syncthreads();
      for (int sh = 128; sh > 0; sh >>= 1) {
        if (tid < sh) red[tid] += red[tid + sh];
        __syncthreads();
      }
      if (tid == 0) musq[b] = red[0];
    } else {
      int row = NLIT + 256 + (b - 256);  // 11008..11135
      for (int j = tid; j < IDIM; j += 256) wt[(size_t)row * IDIM + j] = 0;
    }
  }
}

// ---------------- main fused GEMM (double-buffered, BK=32) ----------------
// Per K-tile: issue 5 copies for k+1 into other buffer, s_waitcnt vmcnt(5)
// + s_barrier (prefetch stays in flight), 24 MFMA, lgkmcnt(0) + s_barrier.
// 16 tiles; stalls overlap across ~3 resident blocks per CU. After the
// epilogue, threadfence + per-m-tile counter; last of 58 blocks runs the
// finale for its 128 rows from L2-hot form_sum/dotbuf.

__global__ __launch_bounds__(256, 3) void dnnf_gemm(
    const u16* __restrict__ xb, const u16* __restrict__ wt,
    const float* __restrict__ bias, float* __restrict__ form_sum,
    float* __restrict__ dotbuf, const float* __restrict__ xsq,
    const float* __restrict__ musq, const float* __restrict__ sigma,
    float* __restrict__ out, u32* __restrict__ cnt) {
  __shared__ __align__(16) char smraw[2 * BUFB];  // 40960 B -> 3 blocks/CU
  __shared__ int slast;
  float* slit = (float*)smraw;                    // epilogue view 32 x SLITP

  const int tid = threadIdx.x;
  const int wave = tid >> 6, lane = tid & 63;
  const int wm = wave & 1, wn = wave >> 1;  // wave tile: 64 rows x 96 cols
  // grid: x = m (64, multiple of 8 -> XCD-pinned m-tiles), y = n (58)
  const int m0 = blockIdx.x * BM, n0 = blockIdx.y * BN;
  const int q = lane >> 4, cn = lane & 15;

  // staging: 16B chunk c = tid + i*256, row r = c>>2, kgroup (c&3)^s(r),
  // s(r) = (r&3)^((r>>2)&3). Since 64|i-stride, s depends only on tid.
  const int kgs = ((tid & 3) ^ ((tid >> 2) & 3) ^ ((tid >> 4) & 3)) * 8;
  const u16* pa = xb + (size_t)(m0 + (tid >> 2)) * IDIM + kgs;
  const u16* pb = wt + (size_t)(n0 + (tid >> 2)) * IDIM + kgs;
  const int dA = tid * 16;           // + i*4096, i<2
  const int dB = ABYTES + tid * 16;  // + i*4096, i<3

  // fragment read: row R (R&3 == cn&3, (R>>2)&3 == (cn>>2)&3), kgroup q
  const int swz16 = (q ^ (cn & 3) ^ ((cn >> 2) & 3)) << 4;
  int offA[4], offB[6];
#pragma unroll
  for (int mf = 0; mf < 4; ++mf)
    offA[mf] = (wm * 64 + mf * 16 + cn) * 64 + swz16;
#pragma unroll
  for (int nf = 0; nf < 6; ++nf)
    offB[nf] = ABYTES + (wn * 96 + nf * 16 + cn) * 64 + swz16;

  f32x4 acc[4][6];
#pragma unroll
  for (int a = 0; a < 4; ++a)
#pragma unroll
    for (int b = 0; b < 6; ++b) acc[a][b] = (f32x4){0.f, 0.f, 0.f, 0.f};

  // prologue: tile 0 -> buffer 0
#pragma unroll
  for (int i = 0; i < 2; ++i)
    async_cp16(pa + (size_t)i * 64 * IDIM, smraw + dA + i * 4096);
#pragma unroll
  for (int i = 0; i < 3; ++i)
    async_cp16(pb + (size_t)i * 64 * IDIM, smraw + dB + i * 4096);
  pa += BK;
  pb += BK;

#pragma unroll
  for (int kt = 0; kt < 16; ++kt) {
    const char* bufc = smraw + (kt & 1) * BUFB;
    if (kt < 15) {
      char* bufn = smraw + ((kt + 1) & 1) * BUFB;
#pragma unroll
      for (int i = 0; i < 2; ++i)
        async_cp16(pa + (size_t)i * 64 * IDIM, bufn + dA + i * 4096);
#pragma unroll
      for (int i = 0; i < 3; ++i)
        async_cp16(pb + (size_t)i * 64 * IDIM, bufn + dB + i * 4096);
      pa += BK;
      pb += BK;
      asm volatile("s_waitcnt vmcnt(5)\n\ts_barrier" ::: "memory");
    } else {
      asm volatile("s_waitcnt vmcnt(0)\n\ts_barrier" ::: "memory");
    }
    bf16x8 af[4], bfr[6];
#pragma unroll
    for (int mf = 0; mf < 4; ++mf)
      af[mf] = *(const bf16x8*)(bufc + offA[mf]);
#pragma unroll
    for (int nf = 0; nf < 6; ++nf)
      bfr[nf] = *(const bf16x8*)(bufc + offB[nf]);
#pragma unroll
    for (int mf = 0; mf < 4; ++mf)
#pragma unroll
      for (int nf = 0; nf < 6; ++nf)
        acc[mf][nf] = __builtin_amdgcn_mfma_f32_16x16x32_bf16(
            af[mf], bfr[nf], acc[mf][nf], 0, 0, 0);
    if (kt < 15)
      asm volatile("s_waitcnt lgkmcnt(0)\n\ts_barrier" ::: "memory");
  }
  __syncthreads();  // full drain before LDS reuse as slit

  if (n0 < NLIT) {
    float bv[6];
#pragma unroll
    for (int nf = 0; nf < 6; ++nf) bv[nf] = bias[n0 + wn * 96 + nf * 16 + cn];

    // four phases of 32 rows; slit tile 32 x SLITP (25 KB <= 40 KB)
#pragma unroll
    for (int ph = 0; ph < 4; ++ph) {
      if (ph) __syncthreads();  // prev-phase reads done before overwrite
      if (wm == (ph >> 1)) {
#pragma unroll
        for (int mh = 0; mh < 2; ++mh) {
          int mf = 2 * (ph & 1) + mh;
#pragma unroll
          for (int nf = 0; nf < 6; ++nf) {
            int col = wn * 96 + nf * 16 + cn;
#pragma unroll
            for (int reg = 0; reg < 4; ++reg) {
              int sr = mh * 16 + q * 4 + reg;
              slit[sr * SLITP + col] = fast_tanh(acc[mf][nf][reg] + bv[nf]);
            }
          }
        }
      }
      __syncthreads();

      int r = tid >> 3, sub = tid & 7;  // 32 rows x 8 threads (24 lits each)
      const float* lrow = slit + r * SLITP + sub * 24;
      int c0 = ((n0 + sub * 24) / 12) * 3;
      size_t grow = (size_t)(m0 + ph * 32 + r) * NFORM;
      float run = 0.f;
      int fprev = -1;
#pragma unroll
      for (int tr = 0; tr < 2; ++tr) {
        const float4 a0 = *(const float4*)(lrow + tr * 12);
        const float4 a1 = *(const float4*)(lrow + tr * 12 + 4);
        const float4 a2 = *(const float4*)(lrow + tr * 12 + 8);
        float s2 = a0.x + a0.y;
        float s4 = a0.z + a0.w + a1.x + a1.y;
        float s6 = a1.z + a1.w + a2.x + a2.y + a2.z + a2.w;
        float v = fast_tanh(s2 - 0.5f) + fast_tanh(s4 - 2.5f) +
                  fast_tanh(s6 - 4.5f);
        int c = c0 + tr * 3;
        int f = (c < 384)    ? (c / 6)
                : (c < 960)  ? 64 + (c - 384) / 9
                : (c < 1728) ? 128 + (c - 960) / 12
                             : 192 + (c - 1728) / 15;
        if (f != fprev) {
          if (fprev >= 0) atomicAdd(form_sum + grow + fprev, run);
          fprev = f;
          run = 0.f;
        }
        run += v;
      }
      atomicAdd(form_sum + grow + fprev, run);
    }
  } else {
    // mu tiles: store raw x.mu dots
#pragma unroll
    for (int nf = 0; nf < 6; ++nf) {
      int col = n0 - NLIT + wn * 96 + nf * 16 + cn;
      if (col < NFORM) {
#pragma unroll
        for (int mf = 0; mf < 4; ++mf)
#pragma unroll
          for (int reg = 0; reg < 4; ++reg) {
            int row = wm * 64 + mf * 16 + q * 4 + reg;
            dotbuf[(size_t)(m0 + row) * NFORM + col] = acc[mf][nf][reg];
          }
      }
    }
  }

  // ---- fused finale: last of the 58 blocks in this m-tile column ----
  __threadfence();  // publish form_sum atomics / dotbuf stores
  if (tid == 0) slast = (atomicAdd(&cnt[blockIdx.x], 1u) == NTILES - 1);
  __syncthreads();
  if (slast) {
    __threadfence();  // acquire: see all other blocks' writes
    const int ln = lane;
    for (int r8 = wave; r8 < BM; r8 += 4) {
      size_t base = (size_t)(m0 + r8) * NFORM;
      float xs = xsq[m0 + r8];
      float e[4], s = 0.f;
#pragma unroll
      for (int j = 0; j < 4; ++j) {
        int f = j * 64 + ln;
        float sq = xs - 2.0f * dotbuf[base + f] + musq[f];
        float sg = sigma[f];
        float p = __expf(-0.5f * sq / (sg * sg));
        e[j] = __expf(2.0f * p);  // TEMPERATURE=2; values in [1, e^2]
        s += e[j];
      }
#pragma unroll
      for (int o = 32; o > 0; o >>= 1) s += __shfl_xor(s, o);
      float inv = __builtin_amdgcn_rcpf(s);
#pragma unroll
      for (int j = 0; j < 4; ++j) {
        int f = j * 64 + ln;
        float dn = fast_tanh(form_sum[base + f] + (float)(6 + 3 * j) - 1.5f);
        out[base + f] = dn * e[j] * inv;
      }
    }
  }
}

// ---------------- launch ----------------

extern "C" void kernel_launch(void* const* d_in, const int* in_sizes, int n_in,
                              void* d_out, int out_size, void* d_ws,
                              size_t ws_size, hipStream_t stream) {
  const float* x = (const float*)d_in[0];
  const float* W = (const float*)d_in[1];
  const float* M = (const float*)d_in[2];
  const float* bias = (const float*)d_in[3];
  const float* mu = (const float*)d_in[4];
  const float* sigma = (const float*)d_in[5];
  float* out = (float*)d_out;

  float* form_sum = (float*)d_ws;                       // 8 MB
  float* dotbuf = form_sum + (size_t)BATCH * NFORM;     // 8 MB
  u16* xb = (u16*)(dotbuf + (size_t)BATCH * NFORM);     // 8 MB
  u16* wt = xb + (size_t)BATCH * IDIM;                  // 11.4 MB
  float* xsq = (float*)(wt + (size_t)WT_ROWS * IDIM);   // 32 KB
  float* musq = xsq + BATCH;                            // 1 KB
  u32* cnt = (u32*)(musq + NFORM);                      // 256 B

  prep_all<<<PREPX_BLKS + PREPW_BLKS + 384, 256, 0, stream>>>(
      x, W, M, mu, xb, wt, xsq, musq, form_sum, cnt);
  // grid: x = m (64, multiple of 8 -> XCD-pinned m-tiles), y = n (58)
  dnnf_gemm<<<dim3(BATCH / BM, WT_ROWS / BN), 256, 0, stream>>>(
      xb, wt, bias, form_sum, dotbuf, xsq, musq, sigma, out, cnt);
}

// Round 7
// 422.466 us; speedup vs baseline: 1.1794x; 1.1794x over previous
//
#include <hip/hip_runtime.h>
#include <hip/hip_cooperative_groups.h>

namespace cg = cooperative_groups;

// DNNF fused pipeline for MI355X (gfx950). R12 = single persistent
// cooperative kernel: prep -> grid.sync -> R7 gemm (grid-stride tiles) ->
// grid.sync -> finale. R11 lesson: per-block __threadfence() serializes on
// L2 writeback (3x); grid.sync is a barrier, not a data-path release, and
// is the guide-blessed mechanism. Non-gemm was a stable ~100us across
// R5-R11 (launch gaps + tails + prep/finale); this removes the boundaries.
// Grid = occ*256 (multiple of 64) so tile walk t+=G keeps x=t%64 pinned to
// blockIdx%64 -> XCD m-tile locality preserved. Gemm K-loop is R7 verbatim
// (132us, best of 6 variants). R9 lesson: no VGPR cap below acc=96.

#define BATCH 8192
#define IDIM 512
#define NFORM 256
#define NLIT 10752
#define WT_ROWS 11136  // NLIT + 256 mu + 128 zero pad; /192 = 58 tiles
#define NTILES 58

#define BM 128
#define BN 192
#define BK 32
#define ABYTES 8192    // 128*32*2
#define BUFB 20480     // one LDS buffer: A 8192 + B 12288
#define SLITP 196      // slit row stride (floats)

#define PREPX 2048
#define PREPW 1344     // 168 l-tiles x 8 k-tiles
#define PREPT 3776     // + 384 mu/zero units

typedef __bf16 bf16x8 __attribute__((ext_vector_type(8)));
typedef float f32x4 __attribute__((ext_vector_type(4)));
typedef unsigned short u16;
typedef unsigned int u32;

__device__ __forceinline__ u16 f2bf(float f) {
  u32 u = __float_as_uint(f);
  u = (u + 0x7fffu + ((u >> 16) & 1u)) >> 16;  // RNE
  return (u16)u;
}

__device__ __forceinline__ float fast_tanh(float x) {
  float e = __expf(2.0f * x);
  return 1.0f - 2.0f * __builtin_amdgcn_rcpf(e + 1.0f);
}

__device__ __forceinline__ void async_cp16(const void* g, void* l) {
  __builtin_amdgcn_global_load_lds(
      (const u32 __attribute__((address_space(1)))*)g,
      (u32 __attribute__((address_space(3)))*)l, 16, 0, 0);
}

__global__ __launch_bounds__(256, 3) void dnnf_fused(
    const float* __restrict__ x, const float* __restrict__ W,
    const float* __restrict__ M, const float* __restrict__ mu,
    const float* __restrict__ bias, const float* __restrict__ sigma,
    u16* __restrict__ xb, u16* __restrict__ wt, float* __restrict__ xsq,
    float* __restrict__ musq, float* __restrict__ form_sum,
    float* __restrict__ dotbuf, float* __restrict__ out) {
  __shared__ __align__(16) char smraw[2 * BUFB];  // 40960 B
  const int tid = threadIdx.x;
  const int wave = tid >> 6, lane = tid & 63;
  const int G = gridDim.x;
  float* lds = (float*)smraw;  // prep view 64 x 65

  // ---------------- phase 1: prep ----------------
  for (int u = blockIdx.x; u < PREPT; u += G) {
    if (u < PREPX) {
      ((uint4*)form_sum)[u * 256 + tid] = make_uint4(0, 0, 0, 0);
      int row = u * 4 + wave;
      const float4* px = (const float4*)(x + (size_t)row * IDIM);
      float4 a = px[lane * 2], b = px[lane * 2 + 1];
      uint4 pk;
      pk.x = (u32)f2bf(a.x) | ((u32)f2bf(a.y) << 16);
      pk.y = (u32)f2bf(a.z) | ((u32)f2bf(a.w) << 16);
      pk.z = (u32)f2bf(b.x) | ((u32)f2bf(b.y) << 16);
      pk.w = (u32)f2bf(b.z) | ((u32)f2bf(b.w) << 16);
      ((uint4*)(xb + (size_t)row * IDIM))[lane] = pk;
      float s = a.x * a.x + a.y * a.y + a.z * a.z + a.w * a.w +
                b.x * b.x + b.y * b.y + b.z * b.z + b.w * b.w;
#pragma unroll
      for (int o = 32; o > 0; o >>= 1) s += __shfl_down(s, o);
      if (lane == 0) xsq[row] = s;
    } else if (u < PREPX + PREPW) {
      int b = u - PREPX;
      int l0 = (b % 168) * 64, k0 = (b / 168) * 64;
#pragma unroll
      for (int j = 0; j < 4; ++j) {
        int idx = tid + j * 256;
        int kk = idx >> 4, l4 = idx & 15;
        size_t g = (size_t)(k0 + kk) * NLIT + l0 + l4 * 4;
        float4 w4 = *(const float4*)(W + g);
        float4 m4 = *(const float4*)(M + g);
        lds[kk * 65 + l4 * 4 + 0] = w4.x * m4.x;
        lds[kk * 65 + l4 * 4 + 1] = w4.y * m4.y;
        lds[kk * 65 + l4 * 4 + 2] = w4.z * m4.z;
        lds[kk * 65 + l4 * 4 + 3] = w4.w * m4.w;
      }
      __syncthreads();
      int l = tid >> 2, kq = tid & 3;
      u32 pk[8];
#pragma unroll
      for (int t = 0; t < 8; ++t) {
        u16 lo = f2bf(lds[(kq * 16 + 2 * t) * 65 + l]);
        u16 hi = f2bf(lds[(kq * 16 + 2 * t + 1) * 65 + l]);
        pk[t] = (u32)lo | ((u32)hi << 16);
      }
      u32* dst = (u32*)(wt + (size_t)(l0 + l) * IDIM + k0 + kq * 16);
      ((uint4*)dst)[0] = make_uint4(pk[0], pk[1], pk[2], pk[3]);
      ((uint4*)dst)[1] = make_uint4(pk[4], pk[5], pk[6], pk[7]);
    } else {
      int b = u - PREPX - PREPW;
      if (b < 256) {
        float s = 0.f;
#pragma unroll
        for (int j = tid; j < IDIM; j += 256) {
          float v = mu[(size_t)b * IDIM + j];
          wt[(size_t)(NLIT + b) * IDIM + j] = f2bf(v);
          s += v * v;
        }
        float* red = lds;
        red[tid] = s;
        __syncthreads();
        for (int sh = 128; sh > 0; sh >>= 1) {
          if (tid < sh) red[tid] += red[tid + sh];
          __syncthreads();
        }
        if (tid == 0) musq[b] = red[0];
      } else {
        int row = NLIT + 256 + (b - 256);  // 11008..11135
        for (int j = tid; j < IDIM; j += 256) wt[(size_t)row * IDIM + j] = 0;
      }
    }
    __syncthreads();  // LDS reuse across units
  }
  cg::this_grid().sync();

  // ---------------- phase 2: gemm (R7 core, grid-stride tiles) ----------
  const int wm = wave & 1, wn = wave >> 1;  // wave tile: 64 rows x 96 cols
  const int q = lane >> 4, cn = lane & 15;
  // staging: 16B chunk c = tid + i*256, row r = c>>2, kgroup (c&3)^s(r),
  // s(r) = (r&3)^((r>>2)&3); 64 | i-stride so s depends only on tid.
  const int kgs = ((tid & 3) ^ ((tid >> 2) & 3) ^ ((tid >> 4) & 3)) * 8;
  const int dA = tid * 16;           // + i*4096, i<2
  const int dB = ABYTES + tid * 16;  // + i*4096, i<3
  const int swz16 = (q ^ (cn & 3) ^ ((cn >> 2) & 3)) << 4;
  int offA[4], offB[6];
#pragma unroll
  for (int mf = 0; mf < 4; ++mf)
    offA[mf] = (wm * 64 + mf * 16 + cn) * 64 + swz16;
#pragma unroll
  for (int nf = 0; nf < 6; ++nf)
    offB[nf] = ABYTES + (wn * 96 + nf * 16 + cn) * 64 + swz16;
  float* slit = (float*)smraw;  // epilogue view 32 x SLITP

  for (int t = blockIdx.x; t < 64 * NTILES; t += G) {
    const int m0 = (t & 63) * BM;  // x = t%64 == blockIdx%64: XCD-pinned
    const int n0 = (t >> 6) * BN;
    __syncthreads();  // prior tile's LDS reads done before restaging

    const u16* pa = xb + (size_t)(m0 + (tid >> 2)) * IDIM + kgs;
    const u16* pb = wt + (size_t)(n0 + (tid >> 2)) * IDIM + kgs;

    f32x4 acc[4][6];
#pragma unroll
    for (int a = 0; a < 4; ++a)
#pragma unroll
      for (int b = 0; b < 6; ++b) acc[a][b] = (f32x4){0.f, 0.f, 0.f, 0.f};

    // prologue: tile 0 -> buffer 0
#pragma unroll
    for (int i = 0; i < 2; ++i)
      async_cp16(pa + (size_t)i * 64 * IDIM, smraw + dA + i * 4096);
#pragma unroll
    for (int i = 0; i < 3; ++i)
      async_cp16(pb + (size_t)i * 64 * IDIM, smraw + dB + i * 4096);
    pa += BK;
    pb += BK;

#pragma unroll
    for (int kt = 0; kt < 16; ++kt) {
      const char* bufc = smraw + (kt & 1) * BUFB;
      if (kt < 15) {
        char* bufn = smraw + ((kt + 1) & 1) * BUFB;
#pragma unroll
        for (int i = 0; i < 2; ++i)
          async_cp16(pa + (size_t)i * 64 * IDIM, bufn + dA + i * 4096);
#pragma unroll
        for (int i = 0; i < 3; ++i)
          async_cp16(pb + (size_t)i * 64 * IDIM, bufn + dB + i * 4096);
        pa += BK;
        pb += BK;
        asm volatile("s_waitcnt vmcnt(5)\n\ts_barrier" ::: "memory");
      } else {
        asm volatile("s_waitcnt vmcnt(0)\n\ts_barrier" ::: "memory");
      }
      bf16x8 af[4], bfr[6];
#pragma unroll
      for (int mf = 0; mf < 4; ++mf)
        af[mf] = *(const bf16x8*)(bufc + offA[mf]);
#pragma unroll
      for (int nf = 0; nf < 6; ++nf)
        bfr[nf] = *(const bf16x8*)(bufc + offB[nf]);
#pragma unroll
      for (int mf = 0; mf < 4; ++mf)
#pragma unroll
        for (int nf = 0; nf < 6; ++nf)
          acc[mf][nf] = __builtin_amdgcn_mfma_f32_16x16x32_bf16(
              af[mf], bfr[nf], acc[mf][nf], 0, 0, 0);
      if (kt < 15)
        asm volatile("s_waitcnt lgkmcnt(0)\n\ts_barrier" ::: "memory");
    }
    __syncthreads();  // full drain before LDS reuse as slit

    if (n0 < NLIT) {
      float bv[6];
#pragma unroll
      for (int nf = 0; nf < 6; ++nf)
        bv[nf] = bias[n0 + wn * 96 + nf * 16 + cn];

      // four phases of 32 rows; slit tile 32 x SLITP (25 KB <= 40 KB)
#pragma unroll
      for (int ph = 0; ph < 4; ++ph) {
        if (ph) __syncthreads();  // prev-phase reads done before overwrite
        if (wm == (ph >> 1)) {
#pragma unroll
          for (int mh = 0; mh < 2; ++mh) {
            int mf = 2 * (ph & 1) + mh;
#pragma unroll
            for (int nf = 0; nf < 6; ++nf) {
              int col = wn * 96 + nf * 16 + cn;
#pragma unroll
              for (int reg = 0; reg < 4; ++reg) {
                int sr = mh * 16 + q * 4 + reg;
                slit[sr * SLITP + col] = fast_tanh(acc[mf][nf][reg] + bv[nf]);
              }
            }
          }
        }
        __syncthreads();

        int r = tid >> 3, sub = tid & 7;  // 32 rows x 8 threads (24 lits)
        const float* lrow = slit + r * SLITP + sub * 24;
        int c0 = ((n0 + sub * 24) / 12) * 3;
        size_t grow = (size_t)(m0 + ph * 32 + r) * NFORM;
        float run = 0.f;
        int fprev = -1;
#pragma unroll
        for (int tr = 0; tr < 2; ++tr) {
          const float4 a0 = *(const float4*)(lrow + tr * 12);
          const float4 a1 = *(const float4*)(lrow + tr * 12 + 4);
          const float4 a2 = *(const float4*)(lrow + tr * 12 + 8);
          float s2 = a0.x + a0.y;
          float s4 = a0.z + a0.w + a1.x + a1.y;
          float s6 = a1.z + a1.w + a2.x + a2.y + a2.z + a2.w;
          float v = fast_tanh(s2 - 0.5f) + fast_tanh(s4 - 2.5f) +
                    fast_tanh(s6 - 4.5f);
          int c = c0 + tr * 3;
          int f = (c < 384)    ? (c / 6)
                  : (c < 960)  ? 64 + (c - 384) / 9
                  : (c < 1728) ? 128 + (c - 960) / 12
                               : 192 + (c - 1728) / 15;
          if (f != fprev) {
            if (fprev >= 0) atomicAdd(form_sum + grow + fprev, run);
            fprev = f;
            run = 0.f;
          }
          run += v;
        }
        atomicAdd(form_sum + grow + fprev, run);
      }
    } else {
      // mu tiles: store raw x.mu dots
#pragma unroll
      for (int nf = 0; nf < 6; ++nf) {
        int col = n0 - NLIT + wn * 96 + nf * 16 + cn;
        if (col < NFORM) {
#pragma unroll
          for (int mf = 0; mf < 4; ++mf)
#pragma unroll
            for (int reg = 0; reg < 4; ++reg) {
              int row = wm * 64 + mf * 16 + q * 4 + reg;
              dotbuf[(size_t)(m0 + row) * NFORM + col] = acc[mf][nf][reg];
            }
        }
      }
    }
  }
  cg::this_grid().sync();

  // ---------------- phase 3: finale (wave-per-row) ----------------
  for (int rq = blockIdx.x; rq < BATCH / 4; rq += G) {
    int r = rq * 4 + wave;
    size_t base = (size_t)r * NFORM;
    float xs = xsq[r];
    float e[4], s = 0.f;
#pragma unroll
    for (int j = 0; j < 4; ++j) {
      int f = j * 64 + lane;
      float sq = xs - 2.0f * dotbuf[base + f] + musq[f];
      float sg = sigma[f];
      float p = __expf(-0.5f * sq / (sg * sg));
      e[j] = __expf(2.0f * p);  // TEMPERATURE=2; values in [1, e^2]
      s += e[j];
    }
#pragma unroll
    for (int o = 32; o > 0; o >>= 1) s += __shfl_xor(s, o);
    float inv = __builtin_amdgcn_rcpf(s);
#pragma unroll
    for (int j = 0; j < 4; ++j) {
      int f = j * 64 + lane;
      float dn = fast_tanh(form_sum[base + f] + (float)(6 + 3 * j) - 1.5f);
      out[base + f] = dn * e[j] * inv;
    }
  }
}

// ---------------- launch ----------------

extern "C" void kernel_launch(void* const* d_in, const int* in_sizes, int n_in,
                              void* d_out, int out_size, void* d_ws,
                              size_t ws_size, hipStream_t stream) {
  const float* x = (const float*)d_in[0];
  const float* W = (const float*)d_in[1];
  const float* M = (const float*)d_in[2];
  const float* bias = (const float*)d_in[3];
  const float* mu = (const float*)d_in[4];
  const float* sigma = (const float*)d_in[5];
  float* out = (float*)d_out;

  float* form_sum = (float*)d_ws;                       // 8 MB
  float* dotbuf = form_sum + (size_t)BATCH * NFORM;     // 8 MB
  u16* xb = (u16*)(dotbuf + (size_t)BATCH * NFORM);     // 8 MB
  u16* wt = xb + (size_t)BATCH * IDIM;                  // 11.4 MB
  float* xsq = (float*)(wt + (size_t)WT_ROWS * IDIM);   // 32 KB
  float* musq = xsq + BATCH;                            // 1 KB

  // co-resident capacity (LDS 40960 -> <=4 blocks/CU; VGPR ~90 -> ok).
  // grid = occ*256 is a multiple of 64 -> XCD m-tile pinning in phase 2.
  int occ = 0;
  hipOccupancyMaxActiveBlocksPerMultiprocessor(
      &occ, reinterpret_cast<const void*>(dnnf_fused), 256, 0);
  if (occ < 1) occ = 2;
  if (occ > 4) occ = 4;
  dim3 grid(occ * 256), block(256);

  void* args[] = {(void*)&x,   (void*)&W,    (void*)&M,        (void*)&mu,
                  (void*)&bias, (void*)&sigma, (void*)&xb,      (void*)&wt,
                  (void*)&xsq, (void*)&musq, (void*)&form_sum, (void*)&dotbuf,
                  (void*)&out};
  hipLaunchCooperativeKernel(reinterpret_cast<const void*>(dnnf_fused), grid,
                             block, args, 0, stream);
}

// Round 8
// 409.021 us; speedup vs baseline: 1.2182x; 1.0329x over previous
//
#include <hip/hip_runtime.h>

// DNNF fused pipeline for MI355X (gfx950). R13 = 3-kernel structure (R12
// lesson: grid-wide sync costs O(100us) on 8 non-coherent XCDs; fusion
// closed) with gemm moved to the unexplored residency quadrant:
// BM=256/BN=192/BK=32, 8 waves, LDS 2x28KB -> 2 blocks/CU = 16 waves/CU,
// and B-side (wt, L3-served) staging traffic halved (365 vs 729 MB).
// Per-wave geometry is R7-verbatim (64x96, acc 4x6, 24 MFMA, same XOR
// swizzle). 512-thr staging: A=2 issues, B=1.5 (guarded); per-wave
// outstanding differs -> wave-uniform divergent vmcnt(4)/vmcnt(3).
// R9 lesson: no VGPR cap below acc=96 (use launch_bounds(512,2)).

#define BATCH 8192
#define IDIM 512
#define NFORM 256
#define NLIT 10752
#define WT_ROWS 11136  // NLIT + 256 mu + 128 zero pad; /192 = 58 tiles

#define BM 256
#define BN 192
#define BK 32
#define ABYTES 16384   // 256*32*2
#define BUFB 28672     // one LDS buffer: A 16384 + B 12288
#define SLITP 196      // slit row stride (floats)

typedef __bf16 bf16x8 __attribute__((ext_vector_type(8)));
typedef float f32x4 __attribute__((ext_vector_type(4)));
typedef unsigned short u16;
typedef unsigned int u32;

__device__ __forceinline__ u16 f2bf(float f) {
  u32 u = __float_as_uint(f);
  u = (u + 0x7fffu + ((u >> 16) & 1u)) >> 16;  // RNE
  return (u16)u;
}

__device__ __forceinline__ float fast_tanh(float x) {
  float e = __expf(2.0f * x);
  return 1.0f - 2.0f * __builtin_amdgcn_rcpf(e + 1.0f);
}

__device__ __forceinline__ void async_cp16(const void* g, void* l) {
  __builtin_amdgcn_global_load_lds(
      (const u32 __attribute__((address_space(1)))*)g,
      (u32 __attribute__((address_space(3)))*)l, 16, 0, 0);
}

// ---------------- fused prep (one dispatch) ----------------

#define PREPX_BLKS 2048
#define PREPW_BLKS 1344  // 168 l-tiles x 8 k-tiles

__global__ __launch_bounds__(256) void prep_all(
    const float* __restrict__ x, const float* __restrict__ W,
    const float* __restrict__ M, const float* __restrict__ mu,
    u16* __restrict__ xb, u16* __restrict__ wt, float* __restrict__ xsq,
    float* __restrict__ musq, float* __restrict__ form_sum) {
  __shared__ float lds[64 * 65];  // 16.6 KB; also reused as red[256]
  const int blk = blockIdx.x, tid = threadIdx.x;

  if (blk < PREPX_BLKS) {
    ((uint4*)form_sum)[blk * 256 + tid] = make_uint4(0, 0, 0, 0);
    int wave = tid >> 6, lane = tid & 63;
    int row = blk * 4 + wave;
    const float4* px = (const float4*)(x + (size_t)row * IDIM);
    float4 a = px[lane * 2], b = px[lane * 2 + 1];
    uint4 pk;
    pk.x = (u32)f2bf(a.x) | ((u32)f2bf(a.y) << 16);
    pk.y = (u32)f2bf(a.z) | ((u32)f2bf(a.w) << 16);
    pk.z = (u32)f2bf(b.x) | ((u32)f2bf(b.y) << 16);
    pk.w = (u32)f2bf(b.z) | ((u32)f2bf(b.w) << 16);
    ((uint4*)(xb + (size_t)row * IDIM))[lane] = pk;
    float s = a.x * a.x + a.y * a.y + a.z * a.z + a.w * a.w +
              b.x * b.x + b.y * b.y + b.z * b.z + b.w * b.w;
#pragma unroll
    for (int o = 32; o > 0; o >>= 1) s += __shfl_down(s, o);
    if (lane == 0) xsq[row] = s;
  } else if (blk < PREPX_BLKS + PREPW_BLKS) {
    int b = blk - PREPX_BLKS;
    int l0 = (b % 168) * 64, k0 = (b / 168) * 64;
#pragma unroll
    for (int j = 0; j < 4; ++j) {
      int idx = tid + j * 256;
      int kk = idx >> 4, l4 = idx & 15;
      size_t g = (size_t)(k0 + kk) * NLIT + l0 + l4 * 4;
      float4 w4 = *(const float4*)(W + g);
      float4 m4 = *(const float4*)(M + g);
      lds[kk * 65 + l4 * 4 + 0] = w4.x * m4.x;
      lds[kk * 65 + l4 * 4 + 1] = w4.y * m4.y;
      lds[kk * 65 + l4 * 4 + 2] = w4.z * m4.z;
      lds[kk * 65 + l4 * 4 + 3] = w4.w * m4.w;
    }
    __syncthreads();
    int l = tid >> 2, kq = tid & 3;
    u32 pk[8];
#pragma unroll
    for (int t = 0; t < 8; ++t) {
      u16 lo = f2bf(lds[(kq * 16 + 2 * t) * 65 + l]);
      u16 hi = f2bf(lds[(kq * 16 + 2 * t + 1) * 65 + l]);
      pk[t] = (u32)lo | ((u32)hi << 16);
    }
    u32* dst = (u32*)(wt + (size_t)(l0 + l) * IDIM + k0 + kq * 16);
    ((uint4*)dst)[0] = make_uint4(pk[0], pk[1], pk[2], pk[3]);
    ((uint4*)dst)[1] = make_uint4(pk[4], pk[5], pk[6], pk[7]);
  } else {
    int b = blk - PREPX_BLKS - PREPW_BLKS;
    if (b < 256) {
      float s = 0.f;
#pragma unroll
      for (int j = tid; j < IDIM; j += 256) {
        float v = mu[(size_t)b * IDIM + j];
        wt[(size_t)(NLIT + b) * IDIM + j] = f2bf(v);
        s += v * v;
      }
      float* red = lds;
      red[tid] = s;
      __syncthreads();
      for (int sh = 128; sh > 0; sh >>= 1) {
        if (tid < sh) red[tid] += red[tid + sh];
        __syncthreads();
      }
      if (tid == 0) musq[b] = red[0];
    } else {
      int row = NLIT + 256 + (b - 256);  // 11008..11135
      for (int j = tid; j < IDIM; j += 256) wt[(size_t)row * IDIM + j] = 0;
    }
  }
}

// ---------------- main fused GEMM (256x192, BK=32, 8 waves) ----------------
// Per K-tile: issue A(2) + B(1 or 2, tid<256) copies for k+1 into the other
// buffer, wave-uniform s_waitcnt vmcnt(4|3) + s_barrier (prior tile landed,
// current in flight), 8+(4|6... per-wave 4A+6B ds_read_b128), 24 MFMA,
// lgkmcnt(0) + s_barrier. 16 tiles; 2 blocks/CU x 8 waves = 16 waves/CU.

__global__ __launch_bounds__(512, 2) void dnnf_gemm(
    const u16* __restrict__ xb, const u16* __restrict__ wt,
    const float* __restrict__ bias, float* __restrict__ form_sum,
    float* __restrict__ dotbuf) {
  __shared__ __align__(16) char smraw[2 * BUFB];  // 57344 B -> 2 blocks/CU
  float* slit = (float*)smraw;                    // epilogue view 32 x SLITP

  const int tid = threadIdx.x;
  const int wave = tid >> 6, lane = tid & 63;
  const int wm = wave & 3, wn = wave >> 2;  // wave tile: 64 rows x 96 cols
  // grid: x = m (32, multiple of 8 -> XCD-pinned m-tiles), y = n (58)
  const int m0 = blockIdx.x * BM, n0 = blockIdx.y * BN;
  const int q = lane >> 4, cn = lane & 15;

  // staging: 16B chunk c in {tid, tid+512}; row r = c>>2, kgroup (c&3)^s(r),
  // s(r) = (r&3)^((r>>2)&3). +512 offset preserves all three terms.
  const int kgs = ((tid & 3) ^ ((tid >> 2) & 3) ^ ((tid >> 4) & 3)) * 8;
  const u16* pa = xb + (size_t)(m0 + (tid >> 2)) * IDIM + kgs;
  const u16* pb = wt + (size_t)(n0 + (tid >> 2)) * IDIM + kgs;
  const int dA = tid * 16;           // + 8192 for second issue (rows 128..255)
  const int dB = ABYTES + tid * 16;  // + 8192 guarded (rows 128..191)

  // fragment read: row R -> slot q^s(R); R&3 == cn&3, (R>>2)&3 == (cn>>2)&3
  const int swz16 = (q ^ (cn & 3) ^ ((cn >> 2) & 3)) << 4;
  int offA[4], offB[6];
#pragma unroll
  for (int mf = 0; mf < 4; ++mf)
    offA[mf] = (wm * 64 + mf * 16 + cn) * 64 + swz16;
#pragma unroll
  for (int nf = 0; nf < 6; ++nf)
    offB[nf] = ABYTES + (wn * 96 + nf * 16 + cn) * 64 + swz16;

  f32x4 acc[4][6];
#pragma unroll
  for (int a = 0; a < 4; ++a)
#pragma unroll
    for (int b = 0; b < 6; ++b) acc[a][b] = (f32x4){0.f, 0.f, 0.f, 0.f};

  // prologue: tile 0 -> buffer 0
  async_cp16(pa, smraw + dA);
  async_cp16(pa + (size_t)128 * IDIM, smraw + dA + 8192);
  async_cp16(pb, smraw + dB);
  if (tid < 256) async_cp16(pb + (size_t)128 * IDIM, smraw + dB + 8192);
  pa += BK;
  pb += BK;

#pragma unroll
  for (int kt = 0; kt < 16; ++kt) {
    const char* bufc = smraw + (kt & 1) * BUFB;
    if (kt < 15) {
      char* bufn = smraw + ((kt + 1) & 1) * BUFB;
      async_cp16(pa, bufn + dA);
      async_cp16(pa + (size_t)128 * IDIM, bufn + dA + 8192);
      async_cp16(pb, bufn + dB);
      if (tid < 256) async_cp16(pb + (size_t)128 * IDIM, bufn + dB + 8192);
      pa += BK;
      pb += BK;
      if (tid < 256)
        asm volatile("s_waitcnt vmcnt(4)\n\ts_barrier" ::: "memory");
      else
        asm volatile("s_waitcnt vmcnt(3)\n\ts_barrier" ::: "memory");
    } else {
      asm volatile("s_waitcnt vmcnt(0)\n\ts_barrier" ::: "memory");
    }
    bf16x8 af[4], bfr[6];
#pragma unroll
    for (int mf = 0; mf < 4; ++mf)
      af[mf] = *(const bf16x8*)(bufc + offA[mf]);
#pragma unroll
    for (int nf = 0; nf < 6; ++nf)
      bfr[nf] = *(const bf16x8*)(bufc + offB[nf]);
#pragma unroll
    for (int mf = 0; mf < 4; ++mf)
#pragma unroll
      for (int nf = 0; nf < 6; ++nf)
        acc[mf][nf] = __builtin_amdgcn_mfma_f32_16x16x32_bf16(
            af[mf], bfr[nf], acc[mf][nf], 0, 0, 0);
    if (kt < 15)
      asm volatile("s_waitcnt lgkmcnt(0)\n\ts_barrier" ::: "memory");
  }
  __syncthreads();  // full drain before LDS reuse as slit

  if (n0 < NLIT) {
    float bv[6];
#pragma unroll
    for (int nf = 0; nf < 6; ++nf) bv[nf] = bias[n0 + wn * 96 + nf * 16 + cn];

    // eight phases of 32 rows; slit tile 32 x SLITP (25 KB <= 56 KB).
    // Writers: waves with wm == ph>>1 (wn 0,1 cover the 192 cols).
#pragma unroll
    for (int ph = 0; ph < 8; ++ph) {
      if (ph) __syncthreads();  // prev-phase reads done before overwrite
      if (wm == (ph >> 1)) {
#pragma unroll
        for (int mh = 0; mh < 2; ++mh) {
          int mf = 2 * (ph & 1) + mh;
#pragma unroll
          for (int nf = 0; nf < 6; ++nf) {
            int col = wn * 96 + nf * 16 + cn;
#pragma unroll
            for (int reg = 0; reg < 4; ++reg) {
              int sr = mh * 16 + q * 4 + reg;
              slit[sr * SLITP + col] = fast_tanh(acc[mf][nf][reg] + bv[nf]);
            }
          }
        }
      }
      __syncthreads();

      int r = tid >> 4, sub = tid & 15;  // 32 rows x 16 threads (12 lits)
      const float* lrow = slit + r * SLITP + sub * 12;
      const float4 a0 = *(const float4*)(lrow);
      const float4 a1 = *(const float4*)(lrow + 4);
      const float4 a2 = *(const float4*)(lrow + 8);
      float s2 = a0.x + a0.y;
      float s4 = a0.z + a0.w + a1.x + a1.y;
      float s6 = a1.z + a1.w + a2.x + a2.y + a2.z + a2.w;
      float v = fast_tanh(s2 - 0.5f) + fast_tanh(s4 - 2.5f) +
                fast_tanh(s6 - 4.5f);
      int c = (n0 / 12 + sub) * 3;
      int f = (c < 384)    ? (c / 6)
              : (c < 960)  ? 64 + (c - 384) / 9
              : (c < 1728) ? 128 + (c - 960) / 12
                           : 192 + (c - 1728) / 15;
      atomicAdd(form_sum + (size_t)(m0 + ph * 32 + r) * NFORM + f, v);
    }
  } else {
    // mu tiles: store raw x.mu dots
#pragma unroll
    for (int nf = 0; nf < 6; ++nf) {
      int col = n0 - NLIT + wn * 96 + nf * 16 + cn;
      if (col < NFORM) {
#pragma unroll
        for (int mf = 0; mf < 4; ++mf)
#pragma unroll
          for (int reg = 0; reg < 4; ++reg) {
            int row = wm * 64 + mf * 16 + q * 4 + reg;
            dotbuf[(size_t)(m0 + row) * NFORM + col] = acc[mf][nf][reg];
          }
      }
    }
  }
}

// ---------------- finale: RBF softmax * dnnf (wave-per-row) ----------------

__global__ __launch_bounds__(256) void finale(
    const float* __restrict__ form_sum, const float* __restrict__ dotbuf,
    const float* __restrict__ xsq, const float* __restrict__ musq,
    const float* __restrict__ sigma, float* __restrict__ out) {
  int wave = threadIdx.x >> 6, lane = threadIdx.x & 63;
  int r = blockIdx.x * 4 + wave;
  size_t base = (size_t)r * NFORM;
  float xs = xsq[r];
  float e[4], s = 0.f;
#pragma unroll
  for (int j = 0; j < 4; ++j) {
    int f = j * 64 + lane;
    float sq = xs - 2.0f * dotbuf[base + f] + musq[f];
    float sg = sigma[f];
    float p = __expf(-0.5f * sq / (sg * sg));
    e[j] = __expf(2.0f * p);  // TEMPERATURE=2; values in [1, e^2]
    s += e[j];
  }
#pragma unroll
  for (int o = 32; o > 0; o >>= 1) s += __shfl_xor(s, o);
  float inv = __builtin_amdgcn_rcpf(s);
#pragma unroll
  for (int j = 0; j < 4; ++j) {
    int f = j * 64 + lane;
    float dn = fast_tanh(form_sum[base + f] + (float)(6 + 3 * j) - 1.5f);
    out[base + f] = dn * e[j] * inv;
  }
}

// ---------------- launch ----------------

extern "C" void kernel_launch(void* const* d_in, const int* in_sizes, int n_in,
                              void* d_out, int out_size, void* d_ws,
                              size_t ws_size, hipStream_t stream) {
  const float* x = (const float*)d_in[0];
  const float* W = (const float*)d_in[1];
  const float* M = (const float*)d_in[2];
  const float* bias = (const float*)d_in[3];
  const float* mu = (const float*)d_in[4];
  const float* sigma = (const float*)d_in[5];
  float* out = (float*)d_out;

  float* form_sum = (float*)d_ws;                       // 8 MB
  float* dotbuf = form_sum + (size_t)BATCH * NFORM;     // 8 MB
  u16* xb = (u16*)(dotbuf + (size_t)BATCH * NFORM);     // 8 MB
  u16* wt = xb + (size_t)BATCH * IDIM;                  // 11.4 MB
  float* xsq = (float*)(wt + (size_t)WT_ROWS * IDIM);   // 32 KB
  float* musq = xsq + BATCH;                            // 1 KB

  prep_all<<<PREPX_BLKS + PREPW_BLKS + 384, 256, 0, stream>>>(
      x, W, M, mu, xb, wt, xsq, musq, form_sum);
  // grid: x = m (32, multiple of 8 -> XCD-pinned m-tiles), y = n (58)
  dnnf_gemm<<<dim3(BATCH / BM, WT_ROWS / BN), 512, 0, stream>>>(xb, wt, bias,
                                                                form_sum, dotbuf);
  finale<<<BATCH / 4, 256, 0, stream>>>(form_sum, dotbuf, xsq, musq, sigma, out);
}

// Round 9
// 375.408 us; speedup vs baseline: 1.3272x; 1.0895x over previous
//
#include <hip/hip_runtime.h>

// DNNF fused pipeline for MI355X (gfx950). R14 = break the register class.
// R13 post-mortem: VGPR_Count excludes AGPRs; R5-R13 all ran acc=96 AGPR +
// ~84-104 VGPR = ~180-200 unified regs -> 2 waves/SIMD = 8 waves/CU. That,
// not LDS or launch bounds, capped occupancy at ~29% all session. R14
// shrinks acc to 48 (wave tile 64x48, BN 192->96) so total ~123 < 128 ->
// 4 waves/SIMD = 16 waves/CU, 2x R7's residency. K-loop recipe is R7
// verbatim otherwise (BK=32, XOR swizzle, 2-barrier dbuf pipeline).
// B staging 1.5 issues/thread (guarded; +64-row chunk has same kgs);
// wave-uniform vmcnt(4|3). Traffic 1.7 GB accepted (R6: traffic slack).

#define BATCH 8192
#define IDIM 512
#define NFORM 256
#define NLIT 10752
#define WT_ROWS 11136  // NLIT + 256 mu + 128 zero pad; /96 = 116 tiles

#define BM 128
#define BN 96
#define BK 32
#define ABYTES 8192    // 128*32*2
#define BBYTES 6144    // 96*32*2
#define BUFB 14336     // one LDS buffer: A 8192 + B 6144
#define SLITP 100      // slit row stride (floats), 96 cols + pad

typedef __bf16 bf16x8 __attribute__((ext_vector_type(8)));
typedef float f32x4 __attribute__((ext_vector_type(4)));
typedef unsigned short u16;
typedef unsigned int u32;

__device__ __forceinline__ u16 f2bf(float f) {
  u32 u = __float_as_uint(f);
  u = (u + 0x7fffu + ((u >> 16) & 1u)) >> 16;  // RNE
  return (u16)u;
}

__device__ __forceinline__ float fast_tanh(float x) {
  float e = __expf(2.0f * x);
  return 1.0f - 2.0f * __builtin_amdgcn_rcpf(e + 1.0f);
}

__device__ __forceinline__ void async_cp16(const void* g, void* l) {
  __builtin_amdgcn_global_load_lds(
      (const u32 __attribute__((address_space(1)))*)g,
      (u32 __attribute__((address_space(3)))*)l, 16, 0, 0);
}

// ---------------- fused prep (one dispatch) ----------------

#define PREPX_BLKS 2048
#define PREPW_BLKS 1344  // 168 l-tiles x 8 k-tiles

__global__ __launch_bounds__(256) void prep_all(
    const float* __restrict__ x, const float* __restrict__ W,
    const float* __restrict__ M, const float* __restrict__ mu,
    u16* __restrict__ xb, u16* __restrict__ wt, float* __restrict__ xsq,
    float* __restrict__ musq, float* __restrict__ form_sum) {
  __shared__ float lds[64 * 65];  // 16.6 KB; also reused as red[256]
  const int blk = blockIdx.x, tid = threadIdx.x;

  if (blk < PREPX_BLKS) {
    ((uint4*)form_sum)[blk * 256 + tid] = make_uint4(0, 0, 0, 0);
    int wave = tid >> 6, lane = tid & 63;
    int row = blk * 4 + wave;
    const float4* px = (const float4*)(x + (size_t)row * IDIM);
    float4 a = px[lane * 2], b = px[lane * 2 + 1];
    uint4 pk;
    pk.x = (u32)f2bf(a.x) | ((u32)f2bf(a.y) << 16);
    pk.y = (u32)f2bf(a.z) | ((u32)f2bf(a.w) << 16);
    pk.z = (u32)f2bf(b.x) | ((u32)f2bf(b.y) << 16);
    pk.w = (u32)f2bf(b.z) | ((u32)f2bf(b.w) << 16);
    ((uint4*)(xb + (size_t)row * IDIM))[lane] = pk;
    float s = a.x * a.x + a.y * a.y + a.z * a.z + a.w * a.w +
              b.x * b.x + b.y * b.y + b.z * b.z + b.w * b.w;
#pragma unroll
    for (int o = 32; o > 0; o >>= 1) s += __shfl_down(s, o);
    if (lane == 0) xsq[row] = s;
  } else if (blk < PREPX_BLKS + PREPW_BLKS) {
    int b = blk - PREPX_BLKS;
    int l0 = (b % 168) * 64, k0 = (b / 168) * 64;
#pragma unroll
    for (int j = 0; j < 4; ++j) {
      int idx = tid + j * 256;
      int kk = idx >> 4, l4 = idx & 15;
      size_t g = (size_t)(k0 + kk) * NLIT + l0 + l4 * 4;
      float4 w4 = *(const float4*)(W + g);
      float4 m4 = *(const float4*)(M + g);
      lds[kk * 65 + l4 * 4 + 0] = w4.x * m4.x;
      lds[kk * 65 + l4 * 4 + 1] = w4.y * m4.y;
      lds[kk * 65 + l4 * 4 + 2] = w4.z * m4.z;
      lds[kk * 65 + l4 * 4 + 3] = w4.w * m4.w;
    }
    __syncthreads();
    int l = tid >> 2, kq = tid & 3;
    u32 pk[8];
#pragma unroll
    for (int t = 0; t < 8; ++t) {
      u16 lo = f2bf(lds[(kq * 16 + 2 * t) * 65 + l]);
      u16 hi = f2bf(lds[(kq * 16 + 2 * t + 1) * 65 + l]);
      pk[t] = (u32)lo | ((u32)hi << 16);
    }
    u32* dst = (u32*)(wt + (size_t)(l0 + l) * IDIM + k0 + kq * 16);
    ((uint4*)dst)[0] = make_uint4(pk[0], pk[1], pk[2], pk[3]);
    ((uint4*)dst)[1] = make_uint4(pk[4], pk[5], pk[6], pk[7]);
  } else {
    int b = blk - PREPX_BLKS - PREPW_BLKS;
    if (b < 256) {
      float s = 0.f;
#pragma unroll
      for (int j = tid; j < IDIM; j += 256) {
        float v = mu[(size_t)b * IDIM + j];
        wt[(size_t)(NLIT + b) * IDIM + j] = f2bf(v);
        s += v * v;
      }
      float* red = lds;
      red[tid] = s;
      __syncthreads();
      for (int sh = 128; sh > 0; sh >>= 1) {
        if (tid < sh) red[tid] += red[tid + sh];
        __syncthreads();
      }
      if (tid == 0) musq[b] = red[0];
    } else {
      int row = NLIT + 256 + (b - 256);  // 11008..11135
      for (int j = tid; j < IDIM; j += 256) wt[(size_t)row * IDIM + j] = 0;
    }
  }
}

// ---------------- main fused GEMM (128x96, BK=32, 4 waves) ----------------
// Per K-tile: issue A(2) + B(1 or 2, tid<128) copies for k+1 into the other
// buffer, wave-uniform s_waitcnt vmcnt(4|3) + s_barrier, per-wave 4A+3B
// ds_read_b128, 12 MFMA, lgkmcnt(0) + s_barrier. 16 tiles. Target:
// 16 waves/CU (4 waves/SIMD) from the 48-AGPR accumulator.

__global__ __launch_bounds__(256, 3) void dnnf_gemm(
    const u16* __restrict__ xb, const u16* __restrict__ wt,
    const float* __restrict__ bias, float* __restrict__ form_sum,
    float* __restrict__ dotbuf) {
  __shared__ __align__(16) char smraw[2 * BUFB];  // 28672 B
  float* slit = (float*)smraw;                    // epilogue view 32 x SLITP

  const int tid = threadIdx.x;
  const int wave = tid >> 6, lane = tid & 63;
  const int wm = wave & 1, wn = wave >> 1;  // wave tile: 64 rows x 48 cols
  // grid: x = m (64, multiple of 8 -> XCD-pinned m-tiles), y = n (116)
  const int m0 = blockIdx.x * BM, n0 = blockIdx.y * BN;
  const int q = lane >> 4, cn = lane & 15;

  // staging: 16B chunk c; row r = c>>2, kgroup (c&3)^s(r), s(r) =
  // (r&3)^((r>>2)&3). A: c = tid, tid+512 (rows 0..127). B: c = tid
  // (rows 0..63) and, for tid<128, c = 256+tid (rows 64..95; +64 rows
  // preserves s since 64>>2 = 16, 16&3 = 0).
  const int kgs = ((tid & 3) ^ ((tid >> 2) & 3) ^ ((tid >> 4) & 3)) * 8;
  const u16* pa = xb + (size_t)(m0 + (tid >> 2)) * IDIM + kgs;
  const u16* pb = wt + (size_t)(n0 + (tid >> 2)) * IDIM + kgs;
  const int dA = tid * 16;           // + 4096 for rows 64..127
  const int dB = ABYTES + tid * 16;  // + 4096 guarded (rows 64..95)

  // fragment read: row R -> slot q^s(R); base rows are 16-multiples so
  // s(R) = (cn&3)^((cn>>2)&3)
  const int swz16 = (q ^ (cn & 3) ^ ((cn >> 2) & 3)) << 4;
  int offA[4], offB[3];
#pragma unroll
  for (int mf = 0; mf < 4; ++mf)
    offA[mf] = (wm * 64 + mf * 16 + cn) * 64 + swz16;
#pragma unroll
  for (int nf = 0; nf < 3; ++nf)
    offB[nf] = ABYTES + (wn * 48 + nf * 16 + cn) * 64 + swz16;

  f32x4 acc[4][3];
#pragma unroll
  for (int a = 0; a < 4; ++a)
#pragma unroll
    for (int b = 0; b < 3; ++b) acc[a][b] = (f32x4){0.f, 0.f, 0.f, 0.f};

  // prologue: tile 0 -> buffer 0
  async_cp16(pa, smraw + dA);
  async_cp16(pa + (size_t)64 * IDIM, smraw + dA + 4096);
  async_cp16(pb, smraw + dB);
  if (wave < 2) async_cp16(pb + (size_t)64 * IDIM, smraw + dB + 4096);
  pa += BK;
  pb += BK;

#pragma unroll
  for (int kt = 0; kt < 16; ++kt) {
    const char* bufc = smraw + (kt & 1) * BUFB;
    if (kt < 15) {
      char* bufn = smraw + ((kt + 1) & 1) * BUFB;
      async_cp16(pa, bufn + dA);
      async_cp16(pa + (size_t)64 * IDIM, bufn + dA + 4096);
      async_cp16(pb, bufn + dB);
      if (wave < 2) async_cp16(pb + (size_t)64 * IDIM, bufn + dB + 4096);
      pa += BK;
      pb += BK;
      if (wave < 2)
        asm volatile("s_waitcnt vmcnt(4)\n\ts_barrier" ::: "memory");
      else
        asm volatile("s_waitcnt vmcnt(3)\n\ts_barrier" ::: "memory");
    } else {
      asm volatile("s_waitcnt vmcnt(0)\n\ts_barrier" ::: "memory");
    }
    bf16x8 af[4], bfr[3];
#pragma unroll
    for (int mf = 0; mf < 4; ++mf)
      af[mf] = *(const bf16x8*)(bufc + offA[mf]);
#pragma unroll
    for (int nf = 0; nf < 3; ++nf)
      bfr[nf] = *(const bf16x8*)(bufc + offB[nf]);
#pragma unroll
    for (int mf = 0; mf < 4; ++mf)
#pragma unroll
      for (int nf = 0; nf < 3; ++nf)
        acc[mf][nf] = __builtin_amdgcn_mfma_f32_16x16x32_bf16(
            af[mf], bfr[nf], acc[mf][nf], 0, 0, 0);
    if (kt < 15)
      asm volatile("s_waitcnt lgkmcnt(0)\n\ts_barrier" ::: "memory");
  }
  __syncthreads();  // full drain before LDS reuse as slit

  if (n0 < NLIT) {
    float bv[3];
#pragma unroll
    for (int nf = 0; nf < 3; ++nf) bv[nf] = bias[n0 + wn * 48 + nf * 16 + cn];

    // four phases of 32 rows; slit tile 32 x SLITP (12.8 KB <= 28 KB).
    // Writers: waves with wm == ph>>1 (wn 0,1 cover the 96 cols).
#pragma unroll
    for (int ph = 0; ph < 4; ++ph) {
      if (ph) __syncthreads();  // prev-phase reads done before overwrite
      if (wm == (ph >> 1)) {
#pragma unroll
        for (int mh = 0; mh < 2; ++mh) {
          int mf = 2 * (ph & 1) + mh;
#pragma unroll
          for (int nf = 0; nf < 3; ++nf) {
            int col = wn * 48 + nf * 16 + cn;
#pragma unroll
            for (int reg = 0; reg < 4; ++reg) {
              int sr = mh * 16 + q * 4 + reg;
              slit[sr * SLITP + col] = fast_tanh(acc[mf][nf][reg] + bv[nf]);
            }
          }
        }
      }
      __syncthreads();

      int r = tid >> 3, sub = tid & 7;  // 32 rows x 8 threads (12 lits each)
      const float* lrow = slit + r * SLITP + sub * 12;
      const float4 a0 = *(const float4*)(lrow);
      const float4 a1 = *(const float4*)(lrow + 4);
      const float4 a2 = *(const float4*)(lrow + 8);
      float s2 = a0.x + a0.y;
      float s4 = a0.z + a0.w + a1.x + a1.y;
      float s6 = a1.z + a1.w + a2.x + a2.y + a2.z + a2.w;
      float v = fast_tanh(s2 - 0.5f) + fast_tanh(s4 - 2.5f) +
                fast_tanh(s6 - 4.5f);
      int c = (n0 / 12 + sub) * 3;
      int f = (c < 384)    ? (c / 6)
              : (c < 960)  ? 64 + (c - 384) / 9
              : (c < 1728) ? 128 + (c - 960) / 12
                           : 192 + (c - 1728) / 15;
      atomicAdd(form_sum + (size_t)(m0 + ph * 32 + r) * NFORM + f, v);
    }
  } else {
    // mu tiles: store raw x.mu dots
#pragma unroll
    for (int nf = 0; nf < 3; ++nf) {
      int col = n0 - NLIT + wn * 48 + nf * 16 + cn;
      if (col < NFORM) {
#pragma unroll
        for (int mf = 0; mf < 4; ++mf)
#pragma unroll
          for (int reg = 0; reg < 4; ++reg) {
            int row = wm * 64 + mf * 16 + q * 4 + reg;
            dotbuf[(size_t)(m0 + row) * NFORM + col] = acc[mf][nf][reg];
          }
      }
    }
  }
}

// ---------------- finale: RBF softmax * dnnf (wave-per-row) ----------------

__global__ __launch_bounds__(256) void finale(
    const float* __restrict__ form_sum, const float* __restrict__ dotbuf,
    const float* __restrict__ xsq, const float* __restrict__ musq,
    const float* __restrict__ sigma, float* __restrict__ out) {
  int wave = threadIdx.x >> 6, lane = threadIdx.x & 63;
  int r = blockIdx.x * 4 + wave;
  size_t base = (size_t)r * NFORM;
  float xs = xsq[r];
  float e[4], s = 0.f;
#pragma unroll
  for (int j = 0; j < 4; ++j) {
    int f = j * 64 + lane;
    float sq = xs - 2.0f * dotbuf[base + f] + musq[f];
    float sg = sigma[f];
    float p = __expf(-0.5f * sq / (sg * sg));
    e[j] = __expf(2.0f * p);  // TEMPERATURE=2; values in [1, e^2]
    s += e[j];
  }
#pragma unroll
  for (int o = 32; o > 0; o >>= 1) s += __shfl_xor(s, o);
  float inv = __builtin_amdgcn_rcpf(s);
#pragma unroll
  for (int j = 0; j < 4; ++j) {
    int f = j * 64 + lane;
    float dn = fast_tanh(form_sum[base + f] + (float)(6 + 3 * j) - 1.5f);
    out[base + f] = dn * e[j] * inv;
  }
}

// ---------------- launch ----------------

extern "C" void kernel_launch(void* const* d_in, const int* in_sizes, int n_in,
                              void* d_out, int out_size, void* d_ws,
                              size_t ws_size, hipStream_t stream) {
  const float* x = (const float*)d_in[0];
  const float* W = (const float*)d_in[1];
  const float* M = (const float*)d_in[2];
  const float* bias = (const float*)d_in[3];
  const float* mu = (const float*)d_in[4];
  const float* sigma = (const float*)d_in[5];
  float* out = (float*)d_out;

  float* form_sum = (float*)d_ws;                       // 8 MB
  float* dotbuf = form_sum + (size_t)BATCH * NFORM;     // 8 MB
  u16* xb = (u16*)(dotbuf + (size_t)BATCH * NFORM);     // 8 MB
  u16* wt = xb + (size_t)BATCH * IDIM;                  // 11.4 MB
  float* xsq = (float*)(wt + (size_t)WT_ROWS * IDIM);   // 32 KB
  float* musq = xsq + BATCH;                            // 1 KB

  prep_all<<<PREPX_BLKS + PREPW_BLKS + 384, 256, 0, stream>>>(
      x, W, M, mu, xb, wt, xsq, musq, form_sum);
  // grid: x = m (64, multiple of 8 -> XCD-pinned m-tiles), y = n (116)
  dnnf_gemm<<<dim3(BATCH / BM, WT_ROWS / BN), 256, 0, stream>>>(xb, wt, bias,
                                                                form_sum, dotbuf);
  finale<<<BATCH / 4, 256, 0, stream>>>(form_sum, dotbuf, xsq, musq, sigma, out);
}